// Round 6
// baseline (357.318 us; speedup 1.0000x reference)
//
#include <hip/hip_runtime.h>
#include <hip/hip_bf16.h>
#include <stdint.h>

typedef _Float16 f16;
typedef __attribute__((ext_vector_type(8))) _Float16 f16x8;
typedef __attribute__((ext_vector_type(4))) _Float16 f16x4;
typedef __attribute__((ext_vector_type(2))) __fp16 fp16x2;
typedef __attribute__((ext_vector_type(4))) float f32x4;

__device__ __forceinline__ void g2l16(const void* g, void* l) {
  __builtin_amdgcn_global_load_lds(
      (const __attribute__((address_space(1))) uint32_t*)g,
      (__attribute__((address_space(3))) uint32_t*)l, 16, 0, 0);
}

__device__ __forceinline__ uint32_t pkrtz(float a, float b) {
  union { fp16x2 h; uint32_t u; } z;
  z.h = __builtin_amdgcn_cvt_pkrtz(a, b);
  return z.u;
}

// ---------------- fused weight transpose + fp32->f16 convert (all 6 weights) ----------------
__global__ __launch_bounds__(256)
void wconv_all_kernel(const float* __restrict__ Wq, const float* __restrict__ Wk,
                      const float* __restrict__ Wv, const float* __restrict__ Wp,
                      const float* __restrict__ Wfc, const float* __restrict__ Wmp,
                      f16* __restrict__ Dq, f16* __restrict__ Dk, f16* __restrict__ Dv,
                      f16* __restrict__ Dp, f16* __restrict__ Dfc, f16* __restrict__ Dmp)
{
  __shared__ float tile[32][33];
  int id = blockIdx.x;
  const float* W; f16* Wt; int K, N, local;
  if      (id < 1024) { W = Wq;  Wt = Dq;  K = 1024; N = 1024; local = id; }
  else if (id < 2048) { W = Wk;  Wt = Dk;  K = 1024; N = 1024; local = id - 1024; }
  else if (id < 3072) { W = Wv;  Wt = Dv;  K = 1024; N = 1024; local = id - 2048; }
  else if (id < 4096) { W = Wp;  Wt = Dp;  K = 1024; N = 1024; local = id - 3072; }
  else if (id < 8192) { W = Wfc; Wt = Dfc; K = 1024; N = 4096; local = id - 4096; }
  else                { W = Wmp; Wt = Dmp; K = 4096; N = 1024; local = id - 8192; }
  int ntx = N >> 5;
  int n0 = (local % ntx) * 32, k0 = (local / ntx) * 32;
  int tx = threadIdx.x & 31, ty = threadIdx.x >> 5;
#pragma unroll
  for (int i = 0; i < 4; ++i)
    tile[ty + 8*i][tx] = W[(size_t)(k0 + ty + 8*i) * N + (n0 + tx)];
  __syncthreads();
#pragma unroll
  for (int i = 0; i < 4; ++i)
    Wt[(size_t)(n0 + ty + 8*i) * K + (k0 + tx)] = (f16)tile[tx][ty + 8*i];
}

// ---------------- scaled = x*lr + x0*lx ; pre = rmsnorm(scaled) ----------------
__global__ __launch_bounds__(256)
void scale_rms_kernel(const float* __restrict__ x, const float* __restrict__ x0,
                      const float* __restrict__ lamR, const float* __restrict__ lamX,
                      float* __restrict__ scaled, f16* __restrict__ pre)
{
  const int C = 1024;
  int row = blockIdx.x, tid = threadIdx.x;
  float lr = lamR[0], lx = lamX[0];
  size_t base = (size_t)row * C;
  float4 xv = ((const float4*)(x + base))[tid];
  float4 zv = ((const float4*)(x0 + base))[tid];
  float4 sv;
  sv.x = xv.x*lr + zv.x*lx;  sv.y = xv.y*lr + zv.y*lx;
  sv.z = xv.z*lr + zv.z*lx;  sv.w = xv.w*lr + zv.w*lx;
  float ss = sv.x*sv.x + sv.y*sv.y + sv.z*sv.z + sv.w*sv.w;
#pragma unroll
  for (int off = 32; off >= 1; off >>= 1) ss += __shfl_xor(ss, off);
  __shared__ float red[4];
  if ((tid & 63) == 0) red[tid >> 6] = ss;
  __syncthreads();
  float tot = red[0] + red[1] + red[2] + red[3];
  float rs = rsqrtf(tot * (1.0f / 1024.0f) + 1e-5f);
  ((float4*)(scaled + base))[tid] = sv;
  f16* p = pre + base + tid * 4;
  p[0] = (f16)(sv.x * rs); p[1] = (f16)(sv.y * rs);
  p[2] = (f16)(sv.z * rs); p[3] = (f16)(sv.w * rs);
}

// ---------------- combine_rms: scaled2 = resid+p0+p1 (f16 partials) ; pre2 = rms ----------------
__global__ __launch_bounds__(256)
void combine_rms_kernel(const float* __restrict__ resid, const f16* __restrict__ p0,
                        const f16* __restrict__ p1, float* __restrict__ scaled2,
                        f16* __restrict__ pre2)
{
  const int C = 1024;
  int row = blockIdx.x, tid = threadIdx.x;
  size_t base = (size_t)row * C;
  float4 rv = ((const float4*)(resid + base))[tid];
  f16x4 av = ((const f16x4*)(p0 + base))[tid];
  f16x4 bv = ((const f16x4*)(p1 + base))[tid];
  float4 sv;
  sv.x = rv.x + (float)av[0] + (float)bv[0];
  sv.y = rv.y + (float)av[1] + (float)bv[1];
  sv.z = rv.z + (float)av[2] + (float)bv[2];
  sv.w = rv.w + (float)av[3] + (float)bv[3];
  float ss = sv.x*sv.x + sv.y*sv.y + sv.z*sv.z + sv.w*sv.w;
#pragma unroll
  for (int off = 32; off >= 1; off >>= 1) ss += __shfl_xor(ss, off);
  __shared__ float red[4];
  if ((tid & 63) == 0) red[tid >> 6] = ss;
  __syncthreads();
  float tot = red[0] + red[1] + red[2] + red[3];
  float rs = rsqrtf(tot * (1.0f / 1024.0f) + 1e-5f);
  ((float4*)(scaled2 + base))[tid] = sv;
  f16* p = pre2 + base + tid * 4;
  p[0] = (f16)(sv.x * rs); p[1] = (f16)(sv.y * rs);
  p[2] = (f16)(sv.z * rs); p[3] = (f16)(sv.w * rs);
}

// ---------------- combine_out: out = resid + sum of 4 f16 partials ----------------
__global__ __launch_bounds__(256)
void combine_out4_kernel(const float* __restrict__ resid, const f16* __restrict__ parts,
                         size_t pstride, float* __restrict__ out)
{
  size_t i = (size_t)blockIdx.x * 256 + threadIdx.x;
  float4 rv = ((const float4*)resid)[i];
  float4 sv = rv;
#pragma unroll
  for (int z = 0; z < 4; ++z) {
    f16x4 av = ((const f16x4*)(parts + z * pstride))[i];
    sv.x += (float)av[0]; sv.y += (float)av[1];
    sv.z += (float)av[2]; sv.w += (float)av[3];
  }
  ((float4*)out)[i] = sv;
}

// ---------------- fused RoPE + rmsnorm on q and k, (B*T, H, 64) f16 ----------------
__global__ __launch_bounds__(256)
void rope_rms_kernel(f16* __restrict__ Xq, f16* __restrict__ Xk,
                     const float* __restrict__ cs, const float* __restrict__ sn)
{
  const int MH = 4096 * 16;
  int ridx = blockIdx.x * 4 + (threadIdx.x >> 6);  // over 2*B*T*H
  f16* X = (ridx < MH) ? Xq : Xk;
  if (ridx >= MH) ridx -= MH;
  int lane = threadIdx.x & 63;
  int h = ridx & 15;
  int bt = ridx >> 4;
  int t = bt & 2047;
  size_t base = (size_t)bt * 1024 + h * 64;
  float xv = (float)X[base + lane];
  float other = __shfl_xor(xv, 32);
  float rot = (lane < 32) ? -other : other;
  float c = cs[t * 64 + lane], s = sn[t * 64 + lane];
  float y = xv * c + rot * s;
  float ss = y * y;
#pragma unroll
  for (int off = 32; off >= 1; off >>= 1) ss += __shfl_xor(ss, off);
  float r = rsqrtf(ss * (1.0f / 64.0f) + 1e-5f);
  X[base + lane] = (f16)(y * r);
}

// ---------------- legacy 128x128 GEMM (kept for proj, small N) ----------------
template<int EPI>
__global__ __launch_bounds__(256)
void gemm_kernel(const f16* __restrict__ A, const f16* __restrict__ Bt,
                 void* __restrict__ out, int M, int N, int K, int nb, int zb)
{
  __shared__ __align__(16) f16 smem[4 * 128 * 32];   // As0|As1|Bs0|Bs1
  const int tid = threadIdx.x;
  const int wave = tid >> 6, lane = tid & 63;
  const int col = lane & 15, quad = lane >> 4;
  const int id = blockIdx.x;
  const int xcd = id & 7, s = id >> 3;
  const int n_i = s % nb;
  const int p = s / nb;
  const int mpx = (M >> 7) >> 3;
  const int zz = p / mpx;
  const int m_i = xcd * mpx + (p % mpx);
  const int m0 = m_i * 128, n0 = n_i * 128;
  const int wm = (wave >> 1) * 64, wn = (wave & 1) * 64;
  const int Ksub = K / zb;
  const int kBeg = zz * Ksub;
  const int nIter = Ksub >> 5;
  f32x4 acc[4][4] = {};

  const size_t rowb = (size_t)K * 2;
  const char* Agp = (const char*)A  + (size_t)m0 * rowb;
  const char* Bgp = (const char*)Bt + (size_t)n0 * rowb;

  const int r_st = (tid >> 2);
  const int cb_st = (tid & 3) << 4;
  const int lb0 = (wave * 64) << 4;
  const int lb1 = (256 + wave * 64) << 4;

#define STAGE(buf, k0)                                                           \
  {                                                                              \
    const size_t koff = (size_t)(k0) * 2;                                        \
    g2l16(Agp + (size_t)r_st * rowb + koff + cb_st,                              \
          (char*)smem + (buf) * 8192 + lb0);                                     \
    g2l16(Agp + (size_t)(r_st + 64) * rowb + koff + cb_st,                       \
          (char*)smem + (buf) * 8192 + lb1);                                     \
    g2l16(Bgp + (size_t)r_st * rowb + koff + cb_st,                              \
          (char*)smem + 16384 + (buf) * 8192 + lb0);                             \
    g2l16(Bgp + (size_t)(r_st + 64) * rowb + koff + cb_st,                       \
          (char*)smem + 16384 + (buf) * 8192 + lb1);                             \
  }

  STAGE(0, kBeg)
  for (int kt = 0; kt < nIter; ++kt) {
    __syncthreads();
    if (kt + 1 < nIter) STAGE((kt + 1) & 1, kBeg + (kt + 1) * 32)
    const f16* As = smem + (kt & 1) * 4096;
    const f16* Bs = smem + 8192 + (kt & 1) * 4096;
    f16x8 af[4], bf[4];
#pragma unroll
    for (int t = 0; t < 4; ++t)
      af[t] = *(const f16x8*)(As + (wm + t*16 + col) * 32 + quad * 8);
#pragma unroll
    for (int t = 0; t < 4; ++t)
      bf[t] = *(const f16x8*)(Bs + (wn + t*16 + col) * 32 + quad * 8);
#pragma unroll
    for (int mt = 0; mt < 4; ++mt)
#pragma unroll
      for (int nt = 0; nt < 4; ++nt)
        acc[mt][nt] = __builtin_amdgcn_mfma_f32_16x16x32_f16(af[mt], bf[nt], acc[mt][nt], 0, 0, 0);
  }
#undef STAGE
  f16* ep = smem + wave * 1024;
  f16* outz = (EPI == 4) ? ((f16*)out + (size_t)zz * M * N) : (f16*)out;
#pragma unroll
  for (int mt = 0; mt < 4; ++mt) {
#pragma unroll
    for (int nt = 0; nt < 4; ++nt) {
#pragma unroll
      for (int r = 0; r < 4; ++r) {
        float v = acc[mt][nt][r];
        if (EPI == 1) { float tv = v > 0.0f ? v : 0.0f; v = tv * tv; }
        ep[(quad * 4 + r) * 64 + ((nt ^ quad) * 16 + col)] = (f16)v;
      }
    }
#pragma unroll
    for (int j = 0; j < 2; ++j) {
      int e = j * 64 + lane;
      int row = e >> 3, rb = e & 7;
      int phys16 = (((rb >> 1) ^ (row >> 2)) << 1) + (rb & 1);
      f16x8 vv = *(const f16x8*)(ep + row * 64 + phys16 * 8);
      int grow = m0 + wm + mt * 16 + row;
      int gcol = n0 + wn + rb * 8;
      *(f16x8*)(outz + (size_t)grow * N + gcol) = vv;
    }
  }
}

// ======================= 256x256 8-wave counted-vmcnt GEMM =======================
__device__ __forceinline__ void stage256(const char* Agp, const char* Bgp, size_t rowb,
                                         char* lds, int st_r, size_t koff, int tid)
{
#pragma unroll
  for (int j = 0; j < 4; ++j) {
    g2l16(Agp + (size_t)(st_r + j * 64) * rowb + koff, lds + j * 8192 + tid * 16);
    g2l16(Bgp + (size_t)(st_r + j * 64) * rowb + koff, lds + 32768 + j * 8192 + tid * 16);
  }
}

template<int EPI>
__global__ __launch_bounds__(512, 2)
void gemm256_kernel(const f16* __restrict__ A, const f16* __restrict__ Bt,
                    void* __restrict__ out, int M, int N, int K, int nb, int zb)
{
  __shared__ __align__(16) f16 smem[65536];   // 128 KB
  const int tid = threadIdx.x;
  const int wave = tid >> 6, lane = tid & 63;
  const int col = lane & 15, quad = lane >> 4;
  const int id = blockIdx.x;
  const int xcd = id & 7, sb = id >> 3;
  const int n_i = sb % nb;
  const int p = sb / nb;
  const int mpx = (M >> 8) >> 3;
  const int zz = p / mpx;
  const int m_i = xcd * mpx + (p % mpx);
  const int m0 = m_i * 256, n0 = n_i * 256;
  const int wm = (wave >> 2) * 128, wn = (wave & 3) * 64;
  const int Ksub = K / zb;
  const int kBeg = zz * Ksub;
  const int ntiles = Ksub >> 6;               // always even here (16)
  f32x4 acc[8][4] = {};

  const size_t rowb = (size_t)K * 2;
  const char* Agp = (const char*)A  + (size_t)m0 * rowb;
  const char* Bgp = (const char*)Bt + (size_t)n0 * rowb;

  const int st_r = tid >> 3;                                   // 0..63 row-in-64-stripe
  const size_t st_so = (size_t)(((tid & 7) ^ ((tid >> 3) & 7)) << 4);  // swizzled src slot

  stage256(Agp, Bgp, rowb, (char*)smem,         st_r, (size_t)kBeg * 2 + st_so, tid);
  stage256(Agp, Bgp, rowb, (char*)smem + 65536, st_r, (size_t)(kBeg + 64) * 2 + st_so, tid);

  for (int t = 0; t < ntiles; ++t) {
    if (t < ntiles - 1) asm volatile("s_waitcnt vmcnt(8)" ::: "memory");
    else                asm volatile("s_waitcnt vmcnt(0)" ::: "memory");
    __builtin_amdgcn_s_barrier();
    asm volatile("" ::: "memory");

    const f16* As = smem + (t & 1) * 32768;
    const f16* Bs = As + 16384;
    f16x8 bf[4][2];
#pragma unroll
    for (int ct = 0; ct < 4; ++ct)
#pragma unroll
      for (int ks = 0; ks < 2; ++ks)
        bf[ct][ks] = *(const f16x8*)(Bs + (wn + ct*16 + col) * 64 +
                                     (((ks*4 + quad) ^ (col & 7)) << 3));
#pragma unroll
    for (int sp = 0; sp < 4; ++sp) {
      f16x8 af[2][2];
#pragma unroll
      for (int i = 0; i < 2; ++i)
#pragma unroll
        for (int ks = 0; ks < 2; ++ks)
          af[i][ks] = *(const f16x8*)(As + (wm + (sp*2 + i)*16 + col) * 64 +
                                      (((ks*4 + quad) ^ (col & 7)) << 3));
      __builtin_amdgcn_s_setprio(1);
#pragma unroll
      for (int i = 0; i < 2; ++i)
#pragma unroll
        for (int ct = 0; ct < 4; ++ct)
#pragma unroll
          for (int ks = 0; ks < 2; ++ks)
            acc[sp*2 + i][ct] = __builtin_amdgcn_mfma_f32_16x16x32_f16(
                af[i][ks], bf[ct][ks], acc[sp*2 + i][ct], 0, 0, 0);
      __builtin_amdgcn_s_setprio(0);
    }

    asm volatile("s_waitcnt lgkmcnt(0)" ::: "memory");
    __builtin_amdgcn_s_barrier();
    asm volatile("" ::: "memory");
    if (t + 2 < ntiles)
      stage256(Agp, Bgp, rowb, (char*)smem + (t & 1) * 65536, st_r,
               (size_t)(kBeg + (t + 2) * 64) * 2 + st_so, tid);
  }

  // epilogue: all LDS free (loop ended with barrier); per-wave 16x64 slab
  f16* ep = smem + wave * 1024;
  f16* outz = (EPI == 4) ? ((f16*)out + (size_t)zz * M * N) : (f16*)out;
#pragma unroll
  for (int mt = 0; mt < 8; ++mt) {
#pragma unroll
    for (int ct = 0; ct < 4; ++ct) {
#pragma unroll
      for (int r = 0; r < 4; ++r) {
        float v = acc[mt][ct][r];
        if (EPI == 1) { float tv = v > 0.0f ? v : 0.0f; v = tv * tv; }
        ep[(quad * 4 + r) * 64 + ((ct ^ quad) * 16 + col)] = (f16)v;
      }
    }
#pragma unroll
    for (int j = 0; j < 2; ++j) {
      int e = j * 64 + lane;
      int row = e >> 3, rb = e & 7;
      int phys16 = (((rb >> 1) ^ (row >> 2)) << 1) + (rb & 1);
      f16x8 vv = *(const f16x8*)(ep + row * 64 + phys16 * 8);
      int grow = m0 + wm + mt * 16 + row;
      int gcol = n0 + wn + rb * 8;
      *(f16x8*)(outz + (size_t)grow * N + gcol) = vv;
    }
  }
}

// ---------------- fused QKV GEMM on the 256x256 structure ----------------
__global__ __launch_bounds__(512, 2)
void gemm256_qkv_kernel(const f16* __restrict__ A, const f16* __restrict__ Bt,
                        f16* __restrict__ qb, f16* __restrict__ kbuf, f16* __restrict__ vtg)
{
  const int K = 1024, nb = 12, ntiles = 16;
  __shared__ __align__(16) f16 smem[65536];
  const int tid = threadIdx.x;
  const int wave = tid >> 6, lane = tid & 63;
  const int col = lane & 15, quad = lane >> 4;
  const int id = blockIdx.x;
  const int xcd = id & 7, sb = id >> 3;
  const int n_i = sb % nb;
  const int m_i = xcd * 2 + (sb / nb);
  const int m0 = m_i * 256, n0 = n_i * 256;
  const int wm = (wave >> 2) * 128, wn = (wave & 3) * 64;
  f32x4 acc[8][4] = {};

  const size_t rowb = (size_t)K * 2;
  const char* Agp = (const char*)A  + (size_t)m0 * rowb;
  const char* Bgp = (const char*)Bt + (size_t)n0 * rowb;

  const int st_r = tid >> 3;
  const size_t st_so = (size_t)(((tid & 7) ^ ((tid >> 3) & 7)) << 4);

  stage256(Agp, Bgp, rowb, (char*)smem,         st_r, st_so, tid);
  stage256(Agp, Bgp, rowb, (char*)smem + 65536, st_r, (size_t)64 * 2 + st_so, tid);

  for (int t = 0; t < ntiles; ++t) {
    if (t < ntiles - 1) asm volatile("s_waitcnt vmcnt(8)" ::: "memory");
    else                asm volatile("s_waitcnt vmcnt(0)" ::: "memory");
    __builtin_amdgcn_s_barrier();
    asm volatile("" ::: "memory");

    const f16* As = smem + (t & 1) * 32768;
    const f16* Bs = As + 16384;
    f16x8 bf[4][2];
#pragma unroll
    for (int ct = 0; ct < 4; ++ct)
#pragma unroll
      for (int ks = 0; ks < 2; ++ks)
        bf[ct][ks] = *(const f16x8*)(Bs + (wn + ct*16 + col) * 64 +
                                     (((ks*4 + quad) ^ (col & 7)) << 3));
#pragma unroll
    for (int sp = 0; sp < 4; ++sp) {
      f16x8 af[2][2];
#pragma unroll
      for (int i = 0; i < 2; ++i)
#pragma unroll
        for (int ks = 0; ks < 2; ++ks)
          af[i][ks] = *(const f16x8*)(As + (wm + (sp*2 + i)*16 + col) * 64 +
                                      (((ks*4 + quad) ^ (col & 7)) << 3));
      __builtin_amdgcn_s_setprio(1);
#pragma unroll
      for (int i = 0; i < 2; ++i)
#pragma unroll
        for (int ct = 0; ct < 4; ++ct)
#pragma unroll
          for (int ks = 0; ks < 2; ++ks)
            acc[sp*2 + i][ct] = __builtin_amdgcn_mfma_f32_16x16x32_f16(
                af[i][ks], bf[ct][ks], acc[sp*2 + i][ct], 0, 0, 0);
      __builtin_amdgcn_s_setprio(0);
    }

    asm volatile("s_waitcnt lgkmcnt(0)" ::: "memory");
    __builtin_amdgcn_s_barrier();
    asm volatile("" ::: "memory");
    if (t + 2 < ntiles)
      stage256(Agp, Bgp, rowb, (char*)smem + (t & 1) * 65536, st_r,
               (size_t)((t + 2) * 64) * 2 + st_so, tid);
  }

  const int cw = n0 + wn;          // wave's 64-col base in 0..3071
  const int sel = cw >> 10;        // 0: Q, 1: K, 2: V (wave-uniform)
  if (sel < 2) {
    f16* dst = (sel == 0) ? qb : kbuf;
    const int cbase = cw & 1023;
    f16* ep = smem + wave * 1024;
#pragma unroll
    for (int mt = 0; mt < 8; ++mt) {
#pragma unroll
      for (int ct = 0; ct < 4; ++ct)
#pragma unroll
        for (int r = 0; r < 4; ++r)
          ep[(quad * 4 + r) * 64 + ((ct ^ quad) * 16 + col)] = (f16)acc[mt][ct][r];
#pragma unroll
      for (int j = 0; j < 2; ++j) {
        int e = j * 64 + lane;
        int row = e >> 3, rb = e & 7;
        int phys16 = (((rb >> 1) ^ (row >> 2)) << 1) + (rb & 1);
        f16x8 vv = *(const f16x8*)(ep + row * 64 + phys16 * 8);
        int grow = m0 + wm + mt * 16 + row;
        *(f16x8*)(dst + (size_t)grow * 1024 + cbase + rb * 8) = vv;
      }
    }
  } else {
    // V: acc[mt][ct][0..3] are 4 consecutive t (rows), same output d -> direct 8B store
#pragma unroll
    for (int mt = 0; mt < 8; ++mt) {
      int t0 = m0 + wm + mt * 16 + quad * 4;
      int b = t0 >> 11, t = t0 & 2047;
#pragma unroll
      for (int ct = 0; ct < 4; ++ct) {
        int dd = (cw & 1023) + ct * 16 + col;   // 0..1023 -> h = dd>>6, d = dd&63
        int hh = dd >> 6, d = dd & 63;
        f16x4 vv;
#pragma unroll
        for (int r = 0; r < 4; ++r) vv[r] = (f16)acc[mt][ct][r];
        *(f16x4*)(vtg + ((size_t)((b * 16 + hh) * 64 + d)) * 2048 + t) = vv;
      }
    }
  }
}

// ---------------- causal flash attention v6: split-K + counted-vmcnt pipeline ----------------
// Grid (bh=32, u=80) as v5. Per k-tile: vmcnt(4) [tile t landed, t+1 in flight] ->
// barrier -> compute -> lgkmcnt(0) -> barrier -> stage(t+2 into freed buffer).
// Never drains vmcnt to 0 in steady state (T4); prefetch distance 2.
__global__ __launch_bounds__(256, 5)
void attn_kernel(const f16* __restrict__ Q, const f16* __restrict__ Kc,
                 const f16* __restrict__ Vt, f16* __restrict__ O,
                 f16* __restrict__ pO, float* __restrict__ pL)
{
  const int T = 2048, C = 1024;
  __shared__ __align__(16) f16 Ks[2][64 * 64];
  __shared__ __align__(16) f16 Vs[2][64 * 64];
  const int tid = threadIdx.x, wave = tid >> 6, lane = tid & 63;
  const int col = lane & 15, quad = lane >> 4;
  const int bh = blockIdx.x, b = bh >> 4, h = bh & 15;

  // u -> (qt, ci); nc = ceil((qt+1)/8)
  const int u = blockIdx.y;
  int qt = 0, acc0 = 0, nc = 1;
  for (int q = 0; q < 32; ++q) {
    int c = (q + 8) >> 3;
    if (u < acc0 + c) { qt = q; nc = c; break; }
    acc0 += c;
  }
  const int ci = u - acc0;
  const int n = qt + 1;
  const int kt0 = (ci * n) / nc, kt1 = ((ci + 1) * n) / nc;
  const int q0 = qt * 64;

  const f16* qb = Q  + ((size_t)b * T) * C + h * 64;
  const f16* kb = Kc + ((size_t)b * T) * C + h * 64;
  const f16* vb = Vt + ((size_t)bh * 64) * T;

  // Q as B-fragment (B = Q^T): lane q=col, c = ks*32 + quad*8 + e
  f16x8 bq[2];
#pragma unroll
  for (int ks = 0; ks < 2; ++ks)
    bq[ks] = *(const f16x8*)(qb + (size_t)(q0 + wave*16 + col) * C + ks*32 + quad*8);

  f32x4 o_acc[4];
#pragma unroll
  for (int dt = 0; dt < 4; ++dt) o_acc[dt] = (f32x4){0.f,0.f,0.f,0.f};
  float l_acc = 0.f;   // sum of this lane's P-values (q = col)

  const int srow = lane >> 3;
  const int sblk = (lane & 7) ^ srow;

  // 4 loads per wave per stage (K0,V0,K1,V1) -> vmcnt gate of 4 per tile in flight
#define STAGEKV(ktile, bi)                                                       \
  {                                                                              \
    const int kk = (ktile) * 64;                                                 \
    _Pragma("unroll")                                                            \
    for (int i = 0; i < 2; ++i) {                                                \
      int r0 = wave * 16 + 8 * i;                                                \
      g2l16(kb + (size_t)(kk + r0 + srow) * C + sblk * 8,                        \
            (char*)Ks[bi] + r0 * 128);                                           \
      g2l16(vb + (size_t)(r0 + srow) * T + kk + sblk * 8,                        \
            (char*)Vs[bi] + r0 * 128);                                           \
    }                                                                            \
  }

  STAGEKV(kt0, 0)
  if (kt0 + 1 < kt1) STAGEKV(kt0 + 1, 1)

  // V chunk offsets (f16 units), kappa order; d&7 == col&7 for all dt
  const int cm = col & 7;
  const int c00 = quad,            c01 = 4 + (quad ^ 1);
  const int c10 = 8 + (quad ^ 2),  c11 = 12 + (quad ^ 3);
  const int o00 = (((c00 >> 1) ^ cm) << 3) + ((c00 & 1) << 2);
  const int o01 = (((c01 >> 1) ^ cm) << 3) + ((c01 & 1) << 2);
  const int o10 = (((c10 >> 1) ^ cm) << 3) + ((c10 & 1) << 2);
  const int o11 = (((c11 >> 1) ^ cm) << 3) + ((c11 & 1) << 2);

  int cur = 0;
  for (int kt = kt0; kt < kt1; ++kt) {
    if (kt + 1 < kt1) asm volatile("s_waitcnt vmcnt(4)" ::: "memory");
    else              asm volatile("s_waitcnt vmcnt(0)" ::: "memory");
    __builtin_amdgcn_s_barrier();
    asm volatile("" ::: "memory");

    // S^T = K * Q^T
    f32x4 s[4];
#pragma unroll
    for (int nt = 0; nt < 4; ++nt) s[nt] = (f32x4){0.f,0.f,0.f,0.f};
    __builtin_amdgcn_s_setprio(1);
#pragma unroll
    for (int ks = 0; ks < 2; ++ks) {
#pragma unroll
      for (int nt = 0; nt < 4; ++nt) {
        int key = nt * 16 + col;
        f16x8 ak = *(const f16x8*)(Ks[cur] + key * 64 + (((ks*4 + quad) ^ (key & 7)) * 8));
        s[nt] = __builtin_amdgcn_mfma_f32_16x16x32_f16(ak, bq[ks], s[nt], 0, 0, 0);
      }
    }
    __builtin_amdgcn_s_setprio(0);

    // softmax (no-max) fully in-register; lane holds P[key=nt*16+quad*4+r][q=col]
    const bool masked = (kt == qt);
    const int qloc = wave * 16 + col;
    uint32_t pk[4][2];
    float l_tile = 0.f;
#pragma unroll
    for (int nt = 0; nt < 4; ++nt) {
      float p[4];
#pragma unroll
      for (int r = 0; r < 4; ++r) {
        float pv = __expf(s[nt][r] * 0.125f);
        if (masked && (nt * 16 + quad * 4 + r > qloc)) pv = 0.0f;
        p[r] = pv;
      }
      l_tile += (p[0] + p[1]) + (p[2] + p[3]);
      pk[nt][0] = pkrtz(p[0], p[1]);
      pk[nt][1] = pkrtz(p[2], p[3]);
    }
    l_acc += l_tile;

    // redistribute to PV A-fragments: ks0 = [own g0 | ^16 g1], ks1 = [^32 g2 | ^48 g3]
    union { uint32_t u[4]; f16x8 v; } pa0, pa1;
    pa0.u[0] = pk[0][0];
    pa0.u[1] = pk[0][1];
    pa0.u[2] = (uint32_t)__shfl_xor((int)pk[1][0], 16);
    pa0.u[3] = (uint32_t)__shfl_xor((int)pk[1][1], 16);
    pa1.u[0] = (uint32_t)__shfl_xor((int)pk[2][0], 32);
    pa1.u[1] = (uint32_t)__shfl_xor((int)pk[2][1], 32);
    pa1.u[2] = (uint32_t)__shfl_xor((int)pk[3][0], 48);
    pa1.u[3] = (uint32_t)__shfl_xor((int)pk[3][1], 48);

    __builtin_amdgcn_s_setprio(1);
#pragma unroll
    for (int dt = 0; dt < 4; ++dt) {
      const f16* vrow = Vs[cur] + (dt * 16 + col) * 64;
      union { struct { f16x4 lo, hi; } p; f16x8 v; } bv0, bv1;
      bv0.p.lo = *(const f16x4*)(vrow + o00);
      bv0.p.hi = *(const f16x4*)(vrow + o01);
      bv1.p.lo = *(const f16x4*)(vrow + o10);
      bv1.p.hi = *(const f16x4*)(vrow + o11);
      o_acc[dt] = __builtin_amdgcn_mfma_f32_16x16x32_f16(pa0.v, bv0.v, o_acc[dt], 0, 0, 0);
      o_acc[dt] = __builtin_amdgcn_mfma_f32_16x16x32_f16(pa1.v, bv1.v, o_acc[dt], 0, 0, 0);
    }
    __builtin_amdgcn_s_setprio(0);

    asm volatile("s_waitcnt lgkmcnt(0)" ::: "memory");
    __builtin_amdgcn_s_barrier();
    asm volatile("" ::: "memory");
    if (kt + 2 < kt1) STAGEKV(kt + 2, cur)
    cur ^= 1;
  }
#undef STAGEKV

  // L[q=col] = sum over quads (each lane ends with L for q=col, replicated)
  l_acc += __shfl_xor(l_acc, 16);
  l_acc += __shfl_xor(l_acc, 32);

  if (nc == 1) {
    float linv[4];
#pragma unroll
    for (int r = 0; r < 4; ++r)
      linv[r] = 1.0f / __shfl(l_acc, quad * 4 + r);
#pragma unroll
    for (int dt = 0; dt < 4; ++dt) {
#pragma unroll
      for (int r = 0; r < 4; ++r) {
        int qr = q0 + wave * 16 + quad * 4 + r;
        float v = o_acc[dt][r] * linv[r];
        O[((size_t)b * T + qr) * C + h * 64 + dt * 16 + col] = (f16)v;
      }
    }
  } else {
    const size_t slot = (size_t)bh * 80 + u;
    f16* po = pO + slot * 4096;
#pragma unroll
    for (int dt = 0; dt < 4; ++dt)
#pragma unroll
      for (int r = 0; r < 4; ++r)
        po[(wave * 16 + quad * 4 + r) * 64 + dt * 16 + col] = (f16)o_acc[dt][r];
    if (quad == 0) pL[slot * 64 + wave * 16 + col] = l_acc;
  }
}

// ---------------- combine split-K attention partials ----------------
// grid (bh=32, qt-8=24). Sums nc partial O tiles (f32), normalizes by summed L.
__global__ __launch_bounds__(256)
void attn_combine_kernel(const f16* __restrict__ pO, const float* __restrict__ pL,
                         f16* __restrict__ O)
{
  const int T = 2048, C = 1024;
  const int bh = blockIdx.x, b = bh >> 4, h = bh & 15;
  const int qt = 8 + blockIdx.y;
  const int nc = (qt + 8) >> 3;
  int pre = 0;
  for (int q = 0; q < qt; ++q) pre += (q + 8) >> 3;
  const size_t slot0 = (size_t)bh * 80 + pre;

  const int t = threadIdx.x;
  const int row = t >> 2, dq = (t & 3) * 16;

  float L = 0.f;
  for (int ci = 0; ci < nc; ++ci) L += pL[(slot0 + ci) * 64 + row];
  const float inv = 1.0f / L;

  float acc[16] = {};
  for (int ci = 0; ci < nc; ++ci) {
    const f16x8* p = (const f16x8*)(pO + (slot0 + ci) * 4096 + row * 64 + dq);
    f16x8 v0 = p[0], v1 = p[1];
#pragma unroll
    for (int j = 0; j < 8; ++j) { acc[j] += (float)v0[j]; acc[8 + j] += (float)v1[j]; }
  }
  f16x8 o0, o1;
#pragma unroll
  for (int j = 0; j < 8; ++j) { o0[j] = (f16)(acc[j] * inv); o1[j] = (f16)(acc[8 + j] * inv); }
  f16* dst = O + ((size_t)b * T + qt * 64 + row) * C + h * 64 + dq;
  ((f16x8*)dst)[0] = o0;
  ((f16x8*)dst)[1] = o1;
}

// ---------------- orchestration ----------------
extern "C" void kernel_launch(void* const* d_in, const int* in_sizes, int n_in,
                              void* d_out, int out_size, void* d_ws, size_t ws_size,
                              hipStream_t stream)
{
  const float* x    = (const float*)d_in[0];
  const float* x0   = (const float*)d_in[1];
  const float* lamR = (const float*)d_in[2];
  const float* lamX = (const float*)d_in[3];
  const float* cs   = (const float*)d_in[4];
  const float* sn   = (const float*)d_in[5];
  const float* Wq   = (const float*)d_in[6];
  const float* Wk   = (const float*)d_in[7];
  const float* Wv   = (const float*)d_in[8];
  const float* Wp   = (const float*)d_in[9];
  const float* Wfc  = (const float*)d_in[10];
  const float* Wmp  = (const float*)d_in[11];
  float* out = (float*)d_out;

  const int B = 2, T = 2048, C = 1024, H = 16;
  const int M = B * T;  // 4096
  const size_t MB = 1ull << 20;
  char* ws = (char*)d_ws;
  f16*   Wqkv_t = (f16*)(ws + 0 * MB);     // 6 MB
  f16*   Wp_t   = (f16*)(ws + 6 * MB);     // 2 MB
  f16*   Wfc_t  = (f16*)(ws + 8 * MB);     // 8 MB
  f16*   Wmp_t  = (f16*)(ws + 16 * MB);    // 8 MB
  float* scaled  = (float*)(ws + 24 * MB); // 16 MB fp32 [later: mlp partials z0,z1]
  f16*   pre     = (f16*)(ws + 40 * MB);   // 8 MB       [later: attnOut -> mlp partial z2]
  f16*   qb      = (f16*)(ws + 48 * MB);   // 8 MB       [later: pre2 -> mlp partial z3]
  f16*   kbuf    = (f16*)(ws + 56 * MB);   // 8 MB
  f16*   vtg     = (f16*)(ws + 64 * MB);   // 8 MB V^T
  float* scaled2 = (float*)(ws + 72 * MB); // 16 MB fp32
  f16*   hbuf    = (f16*)(ws + 88 * MB);   // 32 MB      [first: attn partials, then proj partials]
  f16*   attnOut = pre;
  f16*   pre2    = qb;
  f16*   projP   = (f16*)(ws + 88 * MB);   // 2 x 8 MB f16 (after attn combine)
  f16*   mlpP    = (f16*)(ws + 24 * MB);   // 4 x 8 MB f16 (scaled/pre/qb all dead)
  f16*   attnPO  = (f16*)(ws + 88 * MB);   // 20 MB f16 partial O (dead before projP write)
  float* attnPL  = (float*)(ws + 108 * MB);// 0.65 MB f32 partial L

  dim3 tb(256);
  dim3 tb5(512);
  wconv_all_kernel<<<dim3(12288), tb, 0, stream>>>(
      Wq, Wk, Wv, Wp, Wfc, Wmp,
      Wqkv_t, Wqkv_t + 1024*1024, Wqkv_t + 2048*1024, Wp_t, Wfc_t, Wmp_t);

  scale_rms_kernel<<<M, tb, 0, stream>>>(x, x0, lamR, lamX, scaled, pre);

  // fused QKV GEMM: 256^2 tiles, 192 blocks, counted-vmcnt pipeline
  gemm256_qkv_kernel<<<dim3(192), tb5, 0, stream>>>(pre, Wqkv_t, qb, kbuf, vtg);

  rope_rms_kernel<<<(M * H) / 2, tb, 0, stream>>>(qb, kbuf, cs, sn);

  // split-K attention: uniform chunk grid (32 bh x 80 chunks) + combine
  attn_kernel<<<dim3(B * H, 80), tb, 0, stream>>>(qb, kbuf, vtg, attnOut, attnPO, attnPL);
  attn_combine_kernel<<<dim3(B * H, 24), tb, 0, stream>>>(attnPO, attnPL, attnOut);

  // proj GEMM split-K=2 (512 blocks, legacy 128^2) -> f16 partials ; combine + rms
  gemm_kernel<4><<<dim3(8 * 32 * 2), tb, 0, stream>>>(attnOut, Wp_t, projP, M, C, C, 8, 2);
  combine_rms_kernel<<<M, tb, 0, stream>>>(scaled, projP, projP + (size_t)M*C, scaled2, pre2);

  // fc GEMM + relu^2: 256^2 tiles, 256 blocks
  gemm256_kernel<1><<<dim3(256), tb5, 0, stream>>>(pre2, Wfc_t, hbuf, M, 4*C, C, 16, 1);

  // mlp proj split-K=4: 256^2 tiles, 256 blocks -> f16 partials ; combine into out
  gemm256_kernel<4><<<dim3(256), tb5, 0, stream>>>(hbuf, Wmp_t, mlpP, M, C, 4*C, 4, 4);
  combine_out4_kernel<<<(M*C)/1024, tb, 0, stream>>>(scaled2, mlpP, (size_t)M*C, out);
}

// Round 7
// 335.356 us; speedup vs baseline: 1.0655x; 1.0655x over previous
//
#include <hip/hip_runtime.h>
#include <hip/hip_bf16.h>
#include <stdint.h>

typedef _Float16 f16;
typedef __attribute__((ext_vector_type(8))) _Float16 f16x8;
typedef __attribute__((ext_vector_type(4))) _Float16 f16x4;
typedef __attribute__((ext_vector_type(2))) __fp16 fp16x2;
typedef __attribute__((ext_vector_type(4))) float f32x4;

__device__ __forceinline__ void g2l16(const void* g, void* l) {
  __builtin_amdgcn_global_load_lds(
      (const __attribute__((address_space(1))) uint32_t*)g,
      (__attribute__((address_space(3))) uint32_t*)l, 16, 0, 0);
}

__device__ __forceinline__ uint32_t pkrtz(float a, float b) {
  union { fp16x2 h; uint32_t u; } z;
  z.h = __builtin_amdgcn_cvt_pkrtz(a, b);
  return z.u;
}

// ---------------- fused weight transpose + fp32->f16 convert (all 6 weights) ----------------
__global__ __launch_bounds__(256)
void wconv_all_kernel(const float* __restrict__ Wq, const float* __restrict__ Wk,
                      const float* __restrict__ Wv, const float* __restrict__ Wp,
                      const float* __restrict__ Wfc, const float* __restrict__ Wmp,
                      f16* __restrict__ Dq, f16* __restrict__ Dk, f16* __restrict__ Dv,
                      f16* __restrict__ Dp, f16* __restrict__ Dfc, f16* __restrict__ Dmp)
{
  __shared__ float tile[32][33];
  int id = blockIdx.x;
  const float* W; f16* Wt; int K, N, local;
  if      (id < 1024) { W = Wq;  Wt = Dq;  K = 1024; N = 1024; local = id; }
  else if (id < 2048) { W = Wk;  Wt = Dk;  K = 1024; N = 1024; local = id - 1024; }
  else if (id < 3072) { W = Wv;  Wt = Dv;  K = 1024; N = 1024; local = id - 2048; }
  else if (id < 4096) { W = Wp;  Wt = Dp;  K = 1024; N = 1024; local = id - 3072; }
  else if (id < 8192) { W = Wfc; Wt = Dfc; K = 1024; N = 4096; local = id - 4096; }
  else                { W = Wmp; Wt = Dmp; K = 4096; N = 1024; local = id - 8192; }
  int ntx = N >> 5;
  int n0 = (local % ntx) * 32, k0 = (local / ntx) * 32;
  int tx = threadIdx.x & 31, ty = threadIdx.x >> 5;
#pragma unroll
  for (int i = 0; i < 4; ++i)
    tile[ty + 8*i][tx] = W[(size_t)(k0 + ty + 8*i) * N + (n0 + tx)];
  __syncthreads();
#pragma unroll
  for (int i = 0; i < 4; ++i)
    Wt[(size_t)(n0 + ty + 8*i) * K + (k0 + tx)] = (f16)tile[tx][ty + 8*i];
}

// ---------------- scaled = x*lr + x0*lx ; pre = rmsnorm(scaled) ----------------
__global__ __launch_bounds__(256)
void scale_rms_kernel(const float* __restrict__ x, const float* __restrict__ x0,
                      const float* __restrict__ lamR, const float* __restrict__ lamX,
                      float* __restrict__ scaled, f16* __restrict__ pre)
{
  const int C = 1024;
  int row = blockIdx.x, tid = threadIdx.x;
  float lr = lamR[0], lx = lamX[0];
  size_t base = (size_t)row * C;
  float4 xv = ((const float4*)(x + base))[tid];
  float4 zv = ((const float4*)(x0 + base))[tid];
  float4 sv;
  sv.x = xv.x*lr + zv.x*lx;  sv.y = xv.y*lr + zv.y*lx;
  sv.z = xv.z*lr + zv.z*lx;  sv.w = xv.w*lr + zv.w*lx;
  float ss = sv.x*sv.x + sv.y*sv.y + sv.z*sv.z + sv.w*sv.w;
#pragma unroll
  for (int off = 32; off >= 1; off >>= 1) ss += __shfl_xor(ss, off);
  __shared__ float red[4];
  if ((tid & 63) == 0) red[tid >> 6] = ss;
  __syncthreads();
  float tot = red[0] + red[1] + red[2] + red[3];
  float rs = rsqrtf(tot * (1.0f / 1024.0f) + 1e-5f);
  ((float4*)(scaled + base))[tid] = sv;
  f16* p = pre + base + tid * 4;
  p[0] = (f16)(sv.x * rs); p[1] = (f16)(sv.y * rs);
  p[2] = (f16)(sv.z * rs); p[3] = (f16)(sv.w * rs);
}

// ---------------- combine_rms: scaled2 = resid+p0+p1 (f16 partials) ; pre2 = rms ----------------
__global__ __launch_bounds__(256)
void combine_rms_kernel(const float* __restrict__ resid, const f16* __restrict__ p0,
                        const f16* __restrict__ p1, float* __restrict__ scaled2,
                        f16* __restrict__ pre2)
{
  const int C = 1024;
  int row = blockIdx.x, tid = threadIdx.x;
  size_t base = (size_t)row * C;
  float4 rv = ((const float4*)(resid + base))[tid];
  f16x4 av = ((const f16x4*)(p0 + base))[tid];
  f16x4 bv = ((const f16x4*)(p1 + base))[tid];
  float4 sv;
  sv.x = rv.x + (float)av[0] + (float)bv[0];
  sv.y = rv.y + (float)av[1] + (float)bv[1];
  sv.z = rv.z + (float)av[2] + (float)bv[2];
  sv.w = rv.w + (float)av[3] + (float)bv[3];
  float ss = sv.x*sv.x + sv.y*sv.y + sv.z*sv.z + sv.w*sv.w;
#pragma unroll
  for (int off = 32; off >= 1; off >>= 1) ss += __shfl_xor(ss, off);
  __shared__ float red[4];
  if ((tid & 63) == 0) red[tid >> 6] = ss;
  __syncthreads();
  float tot = red[0] + red[1] + red[2] + red[3];
  float rs = rsqrtf(tot * (1.0f / 1024.0f) + 1e-5f);
  ((float4*)(scaled2 + base))[tid] = sv;
  f16* p = pre2 + base + tid * 4;
  p[0] = (f16)(sv.x * rs); p[1] = (f16)(sv.y * rs);
  p[2] = (f16)(sv.z * rs); p[3] = (f16)(sv.w * rs);
}

// ---------------- combine_out: out = resid + sum of 4 f16 partials ----------------
__global__ __launch_bounds__(256)
void combine_out4_kernel(const float* __restrict__ resid, const f16* __restrict__ parts,
                         size_t pstride, float* __restrict__ out)
{
  size_t i = (size_t)blockIdx.x * 256 + threadIdx.x;
  float4 rv = ((const float4*)resid)[i];
  float4 sv = rv;
#pragma unroll
  for (int z = 0; z < 4; ++z) {
    f16x4 av = ((const f16x4*)(parts + z * pstride))[i];
    sv.x += (float)av[0]; sv.y += (float)av[1];
    sv.z += (float)av[2]; sv.w += (float)av[3];
  }
  ((float4*)out)[i] = sv;
}

// ---------------- legacy 128x128 GEMM (kept for proj, small N) ----------------
template<int EPI>
__global__ __launch_bounds__(256)
void gemm_kernel(const f16* __restrict__ A, const f16* __restrict__ Bt,
                 void* __restrict__ out, int M, int N, int K, int nb, int zb)
{
  __shared__ __align__(16) f16 smem[4 * 128 * 32];   // As0|As1|Bs0|Bs1
  const int tid = threadIdx.x;
  const int wave = tid >> 6, lane = tid & 63;
  const int col = lane & 15, quad = lane >> 4;
  const int id = blockIdx.x;
  const int xcd = id & 7, s = id >> 3;
  const int n_i = s % nb;
  const int p = s / nb;
  const int mpx = (M >> 7) >> 3;
  const int zz = p / mpx;
  const int m_i = xcd * mpx + (p % mpx);
  const int m0 = m_i * 128, n0 = n_i * 128;
  const int wm = (wave >> 1) * 64, wn = (wave & 1) * 64;
  const int Ksub = K / zb;
  const int kBeg = zz * Ksub;
  const int nIter = Ksub >> 5;
  f32x4 acc[4][4] = {};

  const size_t rowb = (size_t)K * 2;
  const char* Agp = (const char*)A  + (size_t)m0 * rowb;
  const char* Bgp = (const char*)Bt + (size_t)n0 * rowb;

  const int r_st = (tid >> 2);
  const int cb_st = (tid & 3) << 4;
  const int lb0 = (wave * 64) << 4;
  const int lb1 = (256 + wave * 64) << 4;

#define STAGE(buf, k0)                                                           \
  {                                                                              \
    const size_t koff = (size_t)(k0) * 2;                                        \
    g2l16(Agp + (size_t)r_st * rowb + koff + cb_st,                              \
          (char*)smem + (buf) * 8192 + lb0);                                     \
    g2l16(Agp + (size_t)(r_st + 64) * rowb + koff + cb_st,                       \
          (char*)smem + (buf) * 8192 + lb1);                                     \
    g2l16(Bgp + (size_t)r_st * rowb + koff + cb_st,                              \
          (char*)smem + 16384 + (buf) * 8192 + lb0);                             \
    g2l16(Bgp + (size_t)(r_st + 64) * rowb + koff + cb_st,                       \
          (char*)smem + 16384 + (buf) * 8192 + lb1);                             \
  }

  STAGE(0, kBeg)
  for (int kt = 0; kt < nIter; ++kt) {
    __syncthreads();
    if (kt + 1 < nIter) STAGE((kt + 1) & 1, kBeg + (kt + 1) * 32)
    const f16* As = smem + (kt & 1) * 4096;
    const f16* Bs = smem + 8192 + (kt & 1) * 4096;
    f16x8 af[4], bf[4];
#pragma unroll
    for (int t = 0; t < 4; ++t)
      af[t] = *(const f16x8*)(As + (wm + t*16 + col) * 32 + quad * 8);
#pragma unroll
    for (int t = 0; t < 4; ++t)
      bf[t] = *(const f16x8*)(Bs + (wn + t*16 + col) * 32 + quad * 8);
#pragma unroll
    for (int mt = 0; mt < 4; ++mt)
#pragma unroll
      for (int nt = 0; nt < 4; ++nt)
        acc[mt][nt] = __builtin_amdgcn_mfma_f32_16x16x32_f16(af[mt], bf[nt], acc[mt][nt], 0, 0, 0);
  }
#undef STAGE
  f16* ep = smem + wave * 1024;
  f16* outz = (EPI == 4) ? ((f16*)out + (size_t)zz * M * N) : (f16*)out;
#pragma unroll
  for (int mt = 0; mt < 4; ++mt) {
#pragma unroll
    for (int nt = 0; nt < 4; ++nt) {
#pragma unroll
      for (int r = 0; r < 4; ++r) {
        float v = acc[mt][nt][r];
        if (EPI == 1) { float tv = v > 0.0f ? v : 0.0f; v = tv * tv; }
        ep[(quad * 4 + r) * 64 + ((nt ^ quad) * 16 + col)] = (f16)v;
      }
    }
#pragma unroll
    for (int j = 0; j < 2; ++j) {
      int e = j * 64 + lane;
      int row = e >> 3, rb = e & 7;
      int phys16 = (((rb >> 1) ^ (row >> 2)) << 1) + (rb & 1);
      f16x8 vv = *(const f16x8*)(ep + row * 64 + phys16 * 8);
      int grow = m0 + wm + mt * 16 + row;
      int gcol = n0 + wn + rb * 8;
      *(f16x8*)(outz + (size_t)grow * N + gcol) = vv;
    }
  }
}

// ======================= 256x256 8-wave counted-vmcnt GEMM =======================
__device__ __forceinline__ void stage256(const char* Agp, const char* Bgp, size_t rowb,
                                         char* lds, int st_r, size_t koff, int tid)
{
#pragma unroll
  for (int j = 0; j < 4; ++j) {
    g2l16(Agp + (size_t)(st_r + j * 64) * rowb + koff, lds + j * 8192 + tid * 16);
    g2l16(Bgp + (size_t)(st_r + j * 64) * rowb + koff, lds + 32768 + j * 8192 + tid * 16);
  }
}

template<int EPI>
__global__ __launch_bounds__(512, 2)
void gemm256_kernel(const f16* __restrict__ A, const f16* __restrict__ Bt,
                    void* __restrict__ out, int M, int N, int K, int nb, int zb)
{
  __shared__ __align__(16) f16 smem[65536];   // 128 KB
  const int tid = threadIdx.x;
  const int wave = tid >> 6, lane = tid & 63;
  const int col = lane & 15, quad = lane >> 4;
  const int id = blockIdx.x;
  const int xcd = id & 7, sb = id >> 3;
  const int n_i = sb % nb;
  const int p = sb / nb;
  const int mpx = (M >> 8) >> 3;
  const int zz = p / mpx;
  const int m_i = xcd * mpx + (p % mpx);
  const int m0 = m_i * 256, n0 = n_i * 256;
  const int wm = (wave >> 2) * 128, wn = (wave & 3) * 64;
  const int Ksub = K / zb;
  const int kBeg = zz * Ksub;
  const int ntiles = Ksub >> 6;               // always even here (16)
  f32x4 acc[8][4] = {};

  const size_t rowb = (size_t)K * 2;
  const char* Agp = (const char*)A  + (size_t)m0 * rowb;
  const char* Bgp = (const char*)Bt + (size_t)n0 * rowb;

  const int st_r = tid >> 3;                                   // 0..63 row-in-64-stripe
  const size_t st_so = (size_t)(((tid & 7) ^ ((tid >> 3) & 7)) << 4);  // swizzled src slot

  stage256(Agp, Bgp, rowb, (char*)smem,         st_r, (size_t)kBeg * 2 + st_so, tid);
  stage256(Agp, Bgp, rowb, (char*)smem + 65536, st_r, (size_t)(kBeg + 64) * 2 + st_so, tid);

  for (int t = 0; t < ntiles; ++t) {
    if (t < ntiles - 1) asm volatile("s_waitcnt vmcnt(8)" ::: "memory");
    else                asm volatile("s_waitcnt vmcnt(0)" ::: "memory");
    __builtin_amdgcn_s_barrier();
    asm volatile("" ::: "memory");

    const f16* As = smem + (t & 1) * 32768;
    const f16* Bs = As + 16384;
    f16x8 bf[4][2];
#pragma unroll
    for (int ct = 0; ct < 4; ++ct)
#pragma unroll
      for (int ks = 0; ks < 2; ++ks)
        bf[ct][ks] = *(const f16x8*)(Bs + (wn + ct*16 + col) * 64 +
                                     (((ks*4 + quad) ^ (col & 7)) << 3));
#pragma unroll
    for (int sp = 0; sp < 4; ++sp) {
      f16x8 af[2][2];
#pragma unroll
      for (int i = 0; i < 2; ++i)
#pragma unroll
        for (int ks = 0; ks < 2; ++ks)
          af[i][ks] = *(const f16x8*)(As + (wm + (sp*2 + i)*16 + col) * 64 +
                                      (((ks*4 + quad) ^ (col & 7)) << 3));
      __builtin_amdgcn_s_setprio(1);
#pragma unroll
      for (int i = 0; i < 2; ++i)
#pragma unroll
        for (int ct = 0; ct < 4; ++ct)
#pragma unroll
          for (int ks = 0; ks < 2; ++ks)
            acc[sp*2 + i][ct] = __builtin_amdgcn_mfma_f32_16x16x32_f16(
                af[i][ks], bf[ct][ks], acc[sp*2 + i][ct], 0, 0, 0);
      __builtin_amdgcn_s_setprio(0);
    }

    asm volatile("s_waitcnt lgkmcnt(0)" ::: "memory");
    __builtin_amdgcn_s_barrier();
    asm volatile("" ::: "memory");
    if (t + 2 < ntiles)
      stage256(Agp, Bgp, rowb, (char*)smem + (t & 1) * 65536, st_r,
               (size_t)(kBeg + (t + 2) * 64) * 2 + st_so, tid);
  }

  // epilogue: all LDS free (loop ended with barrier); per-wave 16x64 slab
  f16* ep = smem + wave * 1024;
  f16* outz = (EPI == 4) ? ((f16*)out + (size_t)zz * M * N) : (f16*)out;
#pragma unroll
  for (int mt = 0; mt < 8; ++mt) {
#pragma unroll
    for (int ct = 0; ct < 4; ++ct) {
#pragma unroll
      for (int r = 0; r < 4; ++r) {
        float v = acc[mt][ct][r];
        if (EPI == 1) { float tv = v > 0.0f ? v : 0.0f; v = tv * tv; }
        ep[(quad * 4 + r) * 64 + ((ct ^ quad) * 16 + col)] = (f16)v;
      }
    }
#pragma unroll
    for (int j = 0; j < 2; ++j) {
      int e = j * 64 + lane;
      int row = e >> 3, rb = e & 7;
      int phys16 = (((rb >> 1) ^ (row >> 2)) << 1) + (rb & 1);
      f16x8 vv = *(const f16x8*)(ep + row * 64 + phys16 * 8);
      int grow = m0 + wm + mt * 16 + row;
      int gcol = n0 + wn + rb * 8;
      *(f16x8*)(outz + (size_t)grow * N + gcol) = vv;
    }
  }
}

// ---------------- fused QKV GEMM + RoPE + rmsnorm epilogue ----------------
// A[4096,1024] @ Wqkv[3072,1024]^T. Q/K waves apply RoPE+rms on the f32
// accumulator before the f16 store: rotate-half partner of d=ct*16+col is
// d^32=(ct^2)*16+col -> SAME lane, register ct^2. rms over head-dim 64 =
// 4 regs (ct) + shfl_xor reduce over the 16-lane col group.
__global__ __launch_bounds__(512, 2)
void gemm256_qkv_kernel(const f16* __restrict__ A, const f16* __restrict__ Bt,
                        f16* __restrict__ qb, f16* __restrict__ kbuf, f16* __restrict__ vtg,
                        const float* __restrict__ cs, const float* __restrict__ sn)
{
  const int K = 1024, nb = 12, ntiles = 16;
  __shared__ __align__(16) f16 smem[65536];
  const int tid = threadIdx.x;
  const int wave = tid >> 6, lane = tid & 63;
  const int col = lane & 15, quad = lane >> 4;
  const int id = blockIdx.x;
  const int xcd = id & 7, sb = id >> 3;
  const int n_i = sb % nb;
  const int m_i = xcd * 2 + (sb / nb);
  const int m0 = m_i * 256, n0 = n_i * 256;
  const int wm = (wave >> 2) * 128, wn = (wave & 3) * 64;
  f32x4 acc[8][4] = {};

  const size_t rowb = (size_t)K * 2;
  const char* Agp = (const char*)A  + (size_t)m0 * rowb;
  const char* Bgp = (const char*)Bt + (size_t)n0 * rowb;

  const int st_r = tid >> 3;
  const size_t st_so = (size_t)(((tid & 7) ^ ((tid >> 3) & 7)) << 4);

  stage256(Agp, Bgp, rowb, (char*)smem,         st_r, st_so, tid);
  stage256(Agp, Bgp, rowb, (char*)smem + 65536, st_r, (size_t)64 * 2 + st_so, tid);

  for (int t = 0; t < ntiles; ++t) {
    if (t < ntiles - 1) asm volatile("s_waitcnt vmcnt(8)" ::: "memory");
    else                asm volatile("s_waitcnt vmcnt(0)" ::: "memory");
    __builtin_amdgcn_s_barrier();
    asm volatile("" ::: "memory");

    const f16* As = smem + (t & 1) * 32768;
    const f16* Bs = As + 16384;
    f16x8 bf[4][2];
#pragma unroll
    for (int ct = 0; ct < 4; ++ct)
#pragma unroll
      for (int ks = 0; ks < 2; ++ks)
        bf[ct][ks] = *(const f16x8*)(Bs + (wn + ct*16 + col) * 64 +
                                     (((ks*4 + quad) ^ (col & 7)) << 3));
#pragma unroll
    for (int sp = 0; sp < 4; ++sp) {
      f16x8 af[2][2];
#pragma unroll
      for (int i = 0; i < 2; ++i)
#pragma unroll
        for (int ks = 0; ks < 2; ++ks)
          af[i][ks] = *(const f16x8*)(As + (wm + (sp*2 + i)*16 + col) * 64 +
                                      (((ks*4 + quad) ^ (col & 7)) << 3));
      __builtin_amdgcn_s_setprio(1);
#pragma unroll
      for (int i = 0; i < 2; ++i)
#pragma unroll
        for (int ct = 0; ct < 4; ++ct)
#pragma unroll
          for (int ks = 0; ks < 2; ++ks)
            acc[sp*2 + i][ct] = __builtin_amdgcn_mfma_f32_16x16x32_f16(
                af[i][ks], bf[ct][ks], acc[sp*2 + i][ct], 0, 0, 0);
      __builtin_amdgcn_s_setprio(0);
    }

    asm volatile("s_waitcnt lgkmcnt(0)" ::: "memory");
    __builtin_amdgcn_s_barrier();
    asm volatile("" ::: "memory");
    if (t + 2 < ntiles)
      stage256(Agp, Bgp, rowb, (char*)smem + (t & 1) * 65536, st_r,
               (size_t)((t + 2) * 64) * 2 + st_so, tid);
  }

  const int cw = n0 + wn;          // wave's 64-col base in 0..3071
  const int sel = cw >> 10;        // 0: Q, 1: K, 2: V (wave-uniform)
  if (sel < 2) {
    f16* dst = (sel == 0) ? qb : kbuf;
    const int cbase = cw & 1023;
    f16* ep = smem + wave * 1024;
#pragma unroll
    for (int mt = 0; mt < 8; ++mt) {
      // RoPE + rmsnorm on acc[mt]: rows are tokens, cols are head-dim d.
#pragma unroll
      for (int r = 0; r < 4; ++r) {
        const int t = (m0 + wm + mt * 16 + quad * 4 + r) & 2047;
        const float* cp = cs + t * 64 + col;
        const float* sp = sn + t * 64 + col;
        float yv[4];
        float ss = 0.f;
#pragma unroll
        for (int ct = 0; ct < 4; ++ct) {
          float c = cp[ct * 16], s = sp[ct * 16];
          float rot = acc[mt][ct ^ 2][r];
          float y = acc[mt][ct][r] * c + (ct < 2 ? -rot : rot) * s;
          yv[ct] = y;
          ss += y * y;
        }
        ss += __shfl_xor(ss, 1, 16);
        ss += __shfl_xor(ss, 2, 16);
        ss += __shfl_xor(ss, 4, 16);
        ss += __shfl_xor(ss, 8, 16);
        float rs = rsqrtf(ss * (1.0f / 64.0f) + 1e-5f);
#pragma unroll
        for (int ct = 0; ct < 4; ++ct) acc[mt][ct][r] = yv[ct] * rs;
      }
#pragma unroll
      for (int ct = 0; ct < 4; ++ct)
#pragma unroll
        for (int r = 0; r < 4; ++r)
          ep[(quad * 4 + r) * 64 + ((ct ^ quad) * 16 + col)] = (f16)acc[mt][ct][r];
#pragma unroll
      for (int j = 0; j < 2; ++j) {
        int e = j * 64 + lane;
        int row = e >> 3, rb = e & 7;
        int phys16 = (((rb >> 1) ^ (row >> 2)) << 1) + (rb & 1);
        f16x8 vv = *(const f16x8*)(ep + row * 64 + phys16 * 8);
        int grow = m0 + wm + mt * 16 + row;
        *(f16x8*)(dst + (size_t)grow * 1024 + cbase + rb * 8) = vv;
      }
    }
  } else {
    // V: acc[mt][ct][0..3] are 4 consecutive t (rows), same output d -> direct 8B store
#pragma unroll
    for (int mt = 0; mt < 8; ++mt) {
      int t0 = m0 + wm + mt * 16 + quad * 4;
      int b = t0 >> 11, t = t0 & 2047;
#pragma unroll
      for (int ct = 0; ct < 4; ++ct) {
        int dd = (cw & 1023) + ct * 16 + col;   // 0..1023 -> h = dd>>6, d = dd&63
        int hh = dd >> 6, d = dd & 63;
        f16x4 vv;
#pragma unroll
        for (int r = 0; r < 4; ++r) vv[r] = (f16)acc[mt][ct][r];
        *(f16x4*)(vtg + ((size_t)((b * 16 + hh) * 64 + d)) * 2048 + t) = vv;
      }
    }
  }
}

// ---------------- causal flash attention v7: paired q-tiles + in-register P ----------------
// Pair q-tile p with 31-p: every block does exactly 33 k-tile compute units.
// 8 waves: waves 0-3 own the hi tile (bound 31-p), waves 4-7 the lo tile (bound p);
// one shared K/V dbuf staging stream. 512 uniform blocks. In-register softmax:
// S^T = mfma(K,Q^T); P packed via cvt_pkrtz, redistributed with shfl_xor 16/32/48;
// V read in kappa order. No Ps LDS buffer, no split-K partials.
__global__ __launch_bounds__(512)
void attn_kernel(const f16* __restrict__ Q, const f16* __restrict__ Kc,
                 const f16* __restrict__ Vt, f16* __restrict__ O)
{
  const int T = 2048, C = 1024;
  __shared__ __align__(16) f16 Ks[2][64 * 64];
  __shared__ __align__(16) f16 Vs[2][64 * 64];
  const int tid = threadIdx.x, wave = tid >> 6, lane = tid & 63;
  const int col = lane & 15, quad = lane >> 4;
  const int bh = blockIdx.x, b = bh >> 4, h = bh & 15;
  const int pr = blockIdx.y;                  // 0..15
  const int grp = wave >> 2;                  // 0: hi tile, 1: lo tile
  const int w4 = wave & 3;
  const int hiB = 31 - pr;
  const int myB = grp ? pr : hiB;             // causal bound (inclusive) == q-tile idx
  const int q0 = myB * 64;

  const f16* qb = Q  + ((size_t)b * T) * C + h * 64;
  const f16* kb = Kc + ((size_t)b * T) * C + h * 64;
  const f16* vb = Vt + ((size_t)bh * 64) * T;

  // Q as B-fragment (B = Q^T): lane q=col, c = ks*32 + quad*8 + e
  f16x8 bq[2];
#pragma unroll
  for (int ks = 0; ks < 2; ++ks)
    bq[ks] = *(const f16x8*)(qb + (size_t)(q0 + w4*16 + col) * C + ks*32 + quad*8);

  f32x4 o_acc[4];
#pragma unroll
  for (int dt = 0; dt < 4; ++dt) o_acc[dt] = (f32x4){0.f,0.f,0.f,0.f};
  float l_acc = 0.f;   // sum of this lane's P-values (q = col)

  const int srow = lane >> 3;
  const int sblk = (lane & 7) ^ srow;
  const int r0 = wave * 8;                    // 8 rows per wave, 8 waves = 64 rows

  g2l16(kb + (size_t)(r0 + srow) * C + sblk * 8, (char*)Ks[0] + r0 * 128);
  g2l16(vb + (size_t)(r0 + srow) * T + sblk * 8, (char*)Vs[0] + r0 * 128);

  // V chunk offsets (f16 units), kappa order; d&7 == col&7 for all dt
  const int cm = col & 7;
  const int c00 = quad,            c01 = 4 + (quad ^ 1);
  const int c10 = 8 + (quad ^ 2),  c11 = 12 + (quad ^ 3);
  const int o00 = (((c00 >> 1) ^ cm) << 3) + ((c00 & 1) << 2);
  const int o01 = (((c01 >> 1) ^ cm) << 3) + ((c01 & 1) << 2);
  const int o10 = (((c10 >> 1) ^ cm) << 3) + ((c10 & 1) << 2);
  const int o11 = (((c11 >> 1) ^ cm) << 3) + ((c11 & 1) << 2);

  int cur = 0;
  for (int kt = 0; kt <= hiB; ++kt) {
    __syncthreads();

    if (kt < hiB) {
      const int ks1 = (kt + 1) * 64;
      g2l16(kb + (size_t)(ks1 + r0 + srow) * C + sblk * 8, (char*)Ks[cur ^ 1] + r0 * 128);
      g2l16(vb + (size_t)(r0 + srow) * T + ks1 + sblk * 8, (char*)Vs[cur ^ 1] + r0 * 128);
    }

    if (kt <= myB) {
      // S^T = K * Q^T
      f32x4 s[4];
#pragma unroll
      for (int nt = 0; nt < 4; ++nt) s[nt] = (f32x4){0.f,0.f,0.f,0.f};
      __builtin_amdgcn_s_setprio(1);
#pragma unroll
      for (int ks = 0; ks < 2; ++ks) {
#pragma unroll
        for (int nt = 0; nt < 4; ++nt) {
          int key = nt * 16 + col;
          f16x8 ak = *(const f16x8*)(Ks[cur] + key * 64 + (((ks*4 + quad) ^ (key & 7)) * 8));
          s[nt] = __builtin_amdgcn_mfma_f32_16x16x32_f16(ak, bq[ks], s[nt], 0, 0, 0);
        }
      }
      __builtin_amdgcn_s_setprio(0);

      // softmax (no-max) in-register; lane holds P[key=nt*16+quad*4+r][q=col]
      const bool masked = (kt == myB);
      const int qloc = w4 * 16 + col;
      uint32_t pk[4][2];
      float l_tile = 0.f;
#pragma unroll
      for (int nt = 0; nt < 4; ++nt) {
        float p[4];
#pragma unroll
        for (int r = 0; r < 4; ++r) {
          float pv = __expf(s[nt][r] * 0.125f);
          if (masked && (nt * 16 + quad * 4 + r > qloc)) pv = 0.0f;
          p[r] = pv;
        }
        l_tile += (p[0] + p[1]) + (p[2] + p[3]);
        pk[nt][0] = pkrtz(p[0], p[1]);
        pk[nt][1] = pkrtz(p[2], p[3]);
      }
      l_acc += l_tile;

      // redistribute to PV A-fragments: ks0 = [own g0 | ^16 g1], ks1 = [^32 g2 | ^48 g3]
      union { uint32_t u[4]; f16x8 v; } pa0, pa1;
      pa0.u[0] = pk[0][0];
      pa0.u[1] = pk[0][1];
      pa0.u[2] = (uint32_t)__shfl_xor((int)pk[1][0], 16);
      pa0.u[3] = (uint32_t)__shfl_xor((int)pk[1][1], 16);
      pa1.u[0] = (uint32_t)__shfl_xor((int)pk[2][0], 32);
      pa1.u[1] = (uint32_t)__shfl_xor((int)pk[2][1], 32);
      pa1.u[2] = (uint32_t)__shfl_xor((int)pk[3][0], 48);
      pa1.u[3] = (uint32_t)__shfl_xor((int)pk[3][1], 48);

      __builtin_amdgcn_s_setprio(1);
#pragma unroll
      for (int dt = 0; dt < 4; ++dt) {
        const f16* vrow = Vs[cur] + (dt * 16 + col) * 64;
        union { struct { f16x4 lo, hi; } p; f16x8 v; } bv0, bv1;
        bv0.p.lo = *(const f16x4*)(vrow + o00);
        bv0.p.hi = *(const f16x4*)(vrow + o01);
        bv1.p.lo = *(const f16x4*)(vrow + o10);
        bv1.p.hi = *(const f16x4*)(vrow + o11);
        o_acc[dt] = __builtin_amdgcn_mfma_f32_16x16x32_f16(pa0.v, bv0.v, o_acc[dt], 0, 0, 0);
        o_acc[dt] = __builtin_amdgcn_mfma_f32_16x16x32_f16(pa1.v, bv1.v, o_acc[dt], 0, 0, 0);
      }
      __builtin_amdgcn_s_setprio(0);
    }
    cur ^= 1;
  }

  // L[q=col]: sum over quads; redistribute to C-layout rows (q = quad*4+r)
  l_acc += __shfl_xor(l_acc, 16);
  l_acc += __shfl_xor(l_acc, 32);
  float linv[4];
#pragma unroll
  for (int r = 0; r < 4; ++r)
    linv[r] = 1.0f / __shfl(l_acc, (wave & 4) * 16 + quad * 4 + r, 64);

#pragma unroll
  for (int dt = 0; dt < 4; ++dt) {
#pragma unroll
    for (int r = 0; r < 4; ++r) {
      int qr = q0 + w4 * 16 + quad * 4 + r;
      float v = o_acc[dt][r] * linv[r];
      O[((size_t)b * T + qr) * C + h * 64 + dt * 16 + col] = (f16)v;
    }
  }
}

// ---------------- orchestration ----------------
extern "C" void kernel_launch(void* const* d_in, const int* in_sizes, int n_in,
                              void* d_out, int out_size, void* d_ws, size_t ws_size,
                              hipStream_t stream)
{
  const float* x    = (const float*)d_in[0];
  const float* x0   = (const float*)d_in[1];
  const float* lamR = (const float*)d_in[2];
  const float* lamX = (const float*)d_in[3];
  const float* cs   = (const float*)d_in[4];
  const float* sn   = (const float*)d_in[5];
  const float* Wq   = (const float*)d_in[6];
  const float* Wk   = (const float*)d_in[7];
  const float* Wv   = (const float*)d_in[8];
  const float* Wp   = (const float*)d_in[9];
  const float* Wfc  = (const float*)d_in[10];
  const float* Wmp  = (const float*)d_in[11];
  float* out = (float*)d_out;

  const int B = 2, T = 2048, C = 1024, H = 16;
  const int M = B * T;  // 4096
  const size_t MB = 1ull << 20;
  char* ws = (char*)d_ws;
  f16*   Wqkv_t = (f16*)(ws + 0 * MB);     // 6 MB
  f16*   Wp_t   = (f16*)(ws + 6 * MB);     // 2 MB
  f16*   Wfc_t  = (f16*)(ws + 8 * MB);     // 8 MB
  f16*   Wmp_t  = (f16*)(ws + 16 * MB);    // 8 MB
  float* scaled  = (float*)(ws + 24 * MB); // 16 MB fp32 [later: mlp partials z0,z1]
  f16*   pre     = (f16*)(ws + 40 * MB);   // 8 MB       [later: attnOut]
  f16*   qb      = (f16*)(ws + 48 * MB);   // 8 MB       [later: pre2]
  f16*   kbuf    = (f16*)(ws + 56 * MB);   // 8 MB
  f16*   vtg     = (f16*)(ws + 64 * MB);   // 8 MB V^T
  float* scaled2 = (float*)(ws + 72 * MB); // 16 MB fp32
  f16*   hbuf    = (f16*)(ws + 88 * MB);   // 32 MB      [first: proj f16 partials 2x8MB]
  f16*   attnOut = pre;
  f16*   pre2    = qb;
  f16*   projP   = (f16*)(ws + 88 * MB);   // 2 x 8 MB f16 (before hbuf written)
  f16*   mlpP    = (f16*)(ws + 24 * MB);   // 4 x 8 MB f16 (scaled/pre/qb all dead)

  dim3 tb(256);
  dim3 tb5(512);
  wconv_all_kernel<<<dim3(12288), tb, 0, stream>>>(
      Wq, Wk, Wv, Wp, Wfc, Wmp,
      Wqkv_t, Wqkv_t + 1024*1024, Wqkv_t + 2048*1024, Wp_t, Wfc_t, Wmp_t);

  scale_rms_kernel<<<M, tb, 0, stream>>>(x, x0, lamR, lamX, scaled, pre);

  // fused QKV GEMM + RoPE + rms: 256^2 tiles, 192 blocks
  gemm256_qkv_kernel<<<dim3(192), tb5, 0, stream>>>(pre, Wqkv_t, qb, kbuf, vtg, cs, sn);

  // paired-causal attention: (bh, pair) grid, 512 uniform blocks, 8 waves
  attn_kernel<<<dim3(B * H, 16), tb5, 0, stream>>>(qb, kbuf, vtg, attnOut);

  // proj GEMM split-K=2 (512 blocks, legacy 128^2) -> f16 partials ; combine + rms
  gemm_kernel<4><<<dim3(8 * 32 * 2), tb, 0, stream>>>(attnOut, Wp_t, projP, M, C, C, 8, 2);
  combine_rms_kernel<<<M, tb, 0, stream>>>(scaled, projP, projP + (size_t)M*C, scaled2, pre2);

  // fc GEMM + relu^2: 256^2 tiles, 256 blocks
  gemm256_kernel<1><<<dim3(256), tb5, 0, stream>>>(pre2, Wfc_t, hbuf, M, 4*C, C, 16, 1);

  // mlp proj split-K=4: 256^2 tiles, 256 blocks -> f16 partials ; combine into out
  gemm256_kernel<4><<<dim3(256), tb5, 0, stream>>>(hbuf, Wmp_t, mlpP, M, C, 4*C, 4, 4);
  combine_out4_kernel<<<(M*C)/1024, tb, 0, stream>>>(scaled2, mlpP, (size_t)M*C, out);
}